// Round 1
// baseline (598.657 us; speedup 1.0000x reference)
//
#include <hip/hip_runtime.h>
#include <hip/hip_bf16.h>

// BNTChannelAttention: qkv = x@W + b; per (b,h): attn = softmax(Q^T K / 8) over
// channel dim (64x64), out = V @ attn.  B=8 N=4096 d_hid=1024 H=16 Dh=64.
//
// Pipeline:
//  1) k_cvt_x   : x fp32 -> bf16 [32768][1024]
//  2) k_wt      : W fp32 [1024][3072] -> bf16 transposed [3072][1024]
//  3) k_gemm1   : m97-structure bf16 MFMA GEMM (128x128 tile, BK=32,
//                 global_load_lds w16); epilogue: +bias, scatter q/k/v bf16
//                 into [BH][N][64] head-major ws
//  4) k_qk      : per (bh, quarter-of-N) 64x64 logit partials via MFMA
//                 (LDS-transposed staging), fp32 partial buffer
//  5) k_softmax : sum partials, *0.125, softmax over e, write attn^T bf16 [e][d]
//  6) k_out     : per (bh, 256-row tile) V @ attn via MFMA, frags direct from
//                 global, store fp32 out[b][n][h*64+e]
//
// ws usage: 284,164,096 bytes.

typedef __attribute__((ext_vector_type(4))) float  f32x4;
typedef __attribute__((ext_vector_type(8))) short  bf16x8;
typedef __attribute__((ext_vector_type(8))) unsigned short u16x8;

typedef __attribute__((address_space(1))) const unsigned int GBUF;
typedef __attribute__((address_space(3))) unsigned int       LBUF;

#define DEVI __device__ __forceinline__

static constexpr int BATCH = 8;
static constexpr int NSEQ  = 4096;
static constexpr int DHID  = 1024;
static constexpr int NHEAD = 16;
static constexpr int DH    = 64;
static constexpr int MROWS = BATCH * NSEQ;   // 32768
static constexpr int N3    = 3 * DHID;       // 3072

DEVI unsigned short f2bf(float f) {
    unsigned int u = __float_as_uint(f);
    u = (u + 0x7fffu + ((u >> 16) & 1u)) >> 16;   // round-to-nearest-even
    return (unsigned short)u;
}

// ---------------------------------------------------------------- 1) x -> bf16
__global__ void k_cvt_x(const float* __restrict__ x, unsigned short* __restrict__ xb, int n8) {
    int i = blockIdx.x * 256 + threadIdx.x;
    int stride = gridDim.x * 256;
    for (; i < n8; i += stride) {
        f32x4 a = *(const f32x4*)(x + (size_t)i * 8);
        f32x4 b = *(const f32x4*)(x + (size_t)i * 8 + 4);
        u16x8 r;
#pragma unroll
        for (int j = 0; j < 4; j++) { r[j] = f2bf(a[j]); r[4 + j] = f2bf(b[j]); }
        *(u16x8*)(xb + (size_t)i * 8) = r;
    }
}

// ------------------------------------------------- 2) W [1024][3072] -> Wt bf16
__global__ void k_wt(const float* __restrict__ W, unsigned short* __restrict__ Wt) {
    __shared__ float s[32][33];
    int c0 = blockIdx.x * 32;      // col in N3
    int k0 = blockIdx.y * 32;      // row in K
    int tx = threadIdx.x & 31, ty = threadIdx.x >> 5;   // 32x8
#pragma unroll
    for (int i = 0; i < 4; i++)
        s[ty + 8 * i][tx] = W[(size_t)(k0 + ty + 8 * i) * N3 + c0 + tx];
    __syncthreads();
#pragma unroll
    for (int i = 0; i < 4; i++)
        Wt[(size_t)(c0 + ty + 8 * i) * DHID + k0 + tx] = f2bf(s[tx][ty + 8 * i]);
}

// ------------------------------------------------------------- 3) QKV GEMM
// A = xb [32768][1024] bf16 row-major-along-K, B = Wt [3072][1024] (B^T form).
// 128x128 tile, BK=32, 4 waves (2x2), each wave 64x64 = 4x4 frags of 16x16x32.
__global__ __launch_bounds__(256, 2) void k_gemm1(
        const unsigned short* __restrict__ xb, const unsigned short* __restrict__ Wt,
        const float* __restrict__ bias,
        unsigned short* __restrict__ Q, unsigned short* __restrict__ Kw,
        unsigned short* __restrict__ V) {
    __shared__ unsigned short As[128 * 32];   // [row][k] 64B rows (gload_lds linear)
    __shared__ unsigned short Bs[128 * 32];   // [col][k]

    int nwg = gridDim.x;
    int cpx = nwg >> 3;                        // 6144 % 8 == 0 -> bijective
    int id  = blockIdx.x;
    int swz = (id & 7) * cpx + (id >> 3);
    int mt = swz / 24, nt = swz % 24;
    int m0 = mt * 128, n0 = nt * 128;

    int t = threadIdx.x, l = t & 63, w = t >> 6;
    int wr = w >> 1, wc = w & 1;

    const unsigned short* aSrc = xb + (size_t)m0 * DHID;
    const unsigned short* bSrc = Wt + (size_t)n0 * DHID;
    int srow  = l >> 2;           // 0..15
    int skoff = (l & 3) * 8;      // shorts

    f32x4 acc[4][4] = {};

    for (int ks = 0; ks < 32; ks++) {
        int kk = ks * 32;
#pragma unroll
        for (int i = 0; i < 2; i++) {
            int r = w * 32 + i * 16 + srow;
            __builtin_amdgcn_global_load_lds(
                (GBUF*)(aSrc + (size_t)r * DHID + kk + skoff),
                (LBUF*)((char*)As + (w * 2 + i) * 1024), 16, 0, 0);
            __builtin_amdgcn_global_load_lds(
                (GBUF*)(bSrc + (size_t)r * DHID + kk + skoff),
                (LBUF*)((char*)Bs + (w * 2 + i) * 1024), 16, 0, 0);
        }
        __syncthreads();
        bf16x8 af[4], bfr[4];
#pragma unroll
        for (int m = 0; m < 4; m++)
            af[m] = *(const bf16x8*)(As + (wr * 64 + m * 16 + (l & 15)) * 32 + (l >> 4) * 8);
#pragma unroll
        for (int n = 0; n < 4; n++)
            bfr[n] = *(const bf16x8*)(Bs + (wc * 64 + n * 16 + (l & 15)) * 32 + (l >> 4) * 8);
#pragma unroll
        for (int m = 0; m < 4; m++)
#pragma unroll
            for (int n = 0; n < 4; n++)
                acc[m][n] = __builtin_amdgcn_mfma_f32_16x16x32_bf16(af[m], bfr[n], acc[m][n], 0, 0, 0);
        __syncthreads();
    }

    // epilogue: +bias, scatter to Q/K/V [b*16+h][n][e] bf16
    int hg   = (n0 + wc * 64) >> 6;       // global head-slot 0..47 (64 cols = 1 head)
    int part = hg >> 4;
    int h    = hg & 15;
    unsigned short* dst = (part == 0) ? Q : ((part == 1) ? Kw : V);
    int b   = m0 >> 12;                   // 128-row tile never straddles batch
    int nnb = m0 & 4095;
    unsigned short* dstp = dst + ((size_t)(b * 16 + h) * NSEQ) * DH;

#pragma unroll
    for (int n = 0; n < 4; n++) {
        int e   = n * 16 + (l & 15);
        float bv = bias[n0 + wc * 64 + n * 16 + (l & 15)];
#pragma unroll
        for (int m = 0; m < 4; m++) {
            int r0 = nnb + wr * 64 + m * 16 + (l >> 4) * 4;
#pragma unroll
            for (int j = 0; j < 4; j++)
                dstp[(size_t)(r0 + j) * DH + e] = f2bf(acc[m][n][j] + bv);
        }
    }
}

// ------------------------------------------- 4) logit partials  P[d][e] (fp32)
// grid = 128 bh * 4 chunks; wg = 256 thr; K-chunk = 1024 rows of N.
__global__ __launch_bounds__(256, 2) void k_qk(
        const unsigned short* __restrict__ Q, const unsigned short* __restrict__ K,
        float* __restrict__ part) {
    __shared__ unsigned short Qt[64 * 40];   // [d][n] pad to 40 shorts (80B rows)
    __shared__ unsigned short Kt[64 * 40];   // 16B-aligned rows, ~2-way banks

    int bid = blockIdx.x;
    int bh = bid >> 2, ch = bid & 3;
    const unsigned short* Qb = Q + ((size_t)bh * NSEQ + ch * 1024) * DH;
    const unsigned short* Kb = K + ((size_t)bh * NSEQ + ch * 1024) * DH;

    int t = threadIdx.x, l = t & 63, w = t >> 6;
    int wr = w >> 1, wc = w & 1;
    int nn = t & 31;          // n within 32-row tile
    int dg = t >> 5;          // d-group 0..7 (8 d's each)

    f32x4 acc[2][2] = {};

    for (int ns = 0; ns < 32; ns++) {
        const size_t ro = (size_t)(ns * 32 + nn) * DH + dg * 8;
        bf16x8 qv = *(const bf16x8*)(Qb + ro);
        bf16x8 kv = *(const bf16x8*)(Kb + ro);
        __syncthreads();                       // prior frag reads done
#pragma unroll
        for (int j = 0; j < 8; j++) {
            Qt[(dg * 8 + j) * 40 + nn] = qv[j];
            Kt[(dg * 8 + j) * 40 + nn] = kv[j];
        }
        __syncthreads();
        bf16x8 a[2], b[2];
#pragma unroll
        for (int m = 0; m < 2; m++)
            a[m] = *(const bf16x8*)(Qt + (wr * 32 + m * 16 + (l & 15)) * 40 + (l >> 4) * 8);
#pragma unroll
        for (int n = 0; n < 2; n++)
            b[n] = *(const bf16x8*)(Kt + (wc * 32 + n * 16 + (l & 15)) * 40 + (l >> 4) * 8);
#pragma unroll
        for (int m = 0; m < 2; m++)
#pragma unroll
            for (int n = 0; n < 2; n++)
                acc[m][n] = __builtin_amdgcn_mfma_f32_16x16x32_bf16(a[m], b[n], acc[m][n], 0, 0, 0);
    }

    float* P = part + ((size_t)ch * 128 + bh) * 4096;
#pragma unroll
    for (int m = 0; m < 2; m++)
#pragma unroll
        for (int n = 0; n < 2; n++)
#pragma unroll
            for (int j = 0; j < 4; j++) {
                int d = wr * 32 + m * 16 + (l >> 4) * 4 + j;
                int e = wc * 32 + n * 16 + (l & 15);
                P[d * 64 + e] = acc[m][n][j];
            }
}

// --------------------------------------- 5) softmax over e, write attn^T bf16
__global__ void k_softmax(const float* __restrict__ part, unsigned short* __restrict__ attn_t) {
    int bh = blockIdx.x;          // 128
    int d  = threadIdx.x;         // 64
    const float* p = part + (size_t)bh * 4096 + d * 64;
    const size_t cs = (size_t)128 * 4096;
    float s[64];
#pragma unroll
    for (int e = 0; e < 64; e++)
        s[e] = (p[e] + p[cs + e] + p[2 * cs + e] + p[3 * cs + e]) * 0.125f;
    float mx = s[0];
#pragma unroll
    for (int e = 1; e < 64; e++) mx = fmaxf(mx, s[e]);
    float sum = 0.f;
#pragma unroll
    for (int e = 0; e < 64; e++) { s[e] = __expf(s[e] - mx); sum += s[e]; }
    float inv = 1.f / sum;
    unsigned short* a = attn_t + (size_t)bh * 4096;
#pragma unroll
    for (int e = 0; e < 64; e++)
        a[e * 64 + d] = f2bf(s[e] * inv);     // [e][d] layout for PV B-frags
}

// ------------------------------------------------------- 6) out = V @ attn
// grid = 128 bh * 16 row-tiles; wave owns 64 rows x 64 cols; no LDS.
__global__ __launch_bounds__(256, 2) void k_out(
        const unsigned short* __restrict__ V, const unsigned short* __restrict__ attn_t,
        float* __restrict__ out) {
    int bid = blockIdx.x;
    int bh = bid >> 4, ntile = bid & 15;
    int b = bh >> 4, h = bh & 15;
    int t = threadIdx.x, l = t & 63, w = t >> 6;
    int r0 = ntile * 256 + w * 64;

    const unsigned short* Vb = V + (size_t)bh * NSEQ * DH;
    const unsigned short* Ab = attn_t + (size_t)bh * 4096;

    bf16x8 bf[4][2];
#pragma unroll
    for (int n = 0; n < 4; n++)
#pragma unroll
        for (int ks = 0; ks < 2; ks++)
            bf[n][ks] = *(const bf16x8*)(Ab + (n * 16 + (l & 15)) * 64 + ks * 32 + (l >> 4) * 8);

    f32x4 acc[4][4] = {};
#pragma unroll
    for (int m = 0; m < 4; m++) {
        const unsigned short* vr = Vb + (size_t)(r0 + m * 16 + (l & 15)) * DH + (l >> 4) * 8;
        bf16x8 av0 = *(const bf16x8*)(vr);
        bf16x8 av1 = *(const bf16x8*)(vr + 32);
#pragma unroll
        for (int n = 0; n < 4; n++) {
            acc[m][n] = __builtin_amdgcn_mfma_f32_16x16x32_bf16(av0, bf[n][0], acc[m][n], 0, 0, 0);
            acc[m][n] = __builtin_amdgcn_mfma_f32_16x16x32_bf16(av1, bf[n][1], acc[m][n], 0, 0, 0);
        }
    }

    float* ob = out + (size_t)b * NSEQ * DHID + (size_t)h * DH;
#pragma unroll
    for (int m = 0; m < 4; m++)
#pragma unroll
        for (int n = 0; n < 4; n++)
#pragma unroll
            for (int j = 0; j < 4; j++) {
                int nn = r0 + m * 16 + (l >> 4) * 4 + j;
                int e  = n * 16 + (l & 15);
                ob[(size_t)nn * DHID + e] = acc[m][n][j];
            }
}

// ---------------------------------------------------------------- launcher
extern "C" void kernel_launch(void* const* d_in, const int* in_sizes, int n_in,
                              void* d_out, int out_size, void* d_ws, size_t ws_size,
                              hipStream_t stream) {
    const float* x    = (const float*)d_in[0];
    const float* W    = (const float*)d_in[1];
    const float* bias = (const float*)d_in[2];
    float* out = (float*)d_out;

    char* wsp = (char*)d_ws;
    unsigned short* xb   = (unsigned short*)(wsp);                 //  67,108,864 B
    unsigned short* Wt   = (unsigned short*)(wsp + 67108864);      //   6,291,456 B
    unsigned short* Qw   = (unsigned short*)(wsp + 73400320);      //  67,108,864 B
    unsigned short* Kww  = (unsigned short*)(wsp + 140509184);     //  67,108,864 B
    unsigned short* Vw   = (unsigned short*)(wsp + 207618048);     //  67,108,864 B
    float*          part = (float*)(wsp + 274726912);              //   8,388,608 B
    unsigned short* attn = (unsigned short*)(wsp + 283115520);     //   1,048,576 B
    // total 284,164,096 bytes of ws

    k_cvt_x<<<2048, 256, 0, stream>>>(x, xb, MROWS * DHID / 8);
    k_wt<<<dim3(N3 / 32, DHID / 32), 256, 0, stream>>>(W, Wt);
    k_gemm1<<<(MROWS / 128) * (N3 / 128), 256, 0, stream>>>(xb, Wt, bias, Qw, Kww, Vw);
    k_qk<<<128 * 4, 256, 0, stream>>>(Qw, Kww, part);
    k_softmax<<<128, 64, 0, stream>>>(part, attn);
    k_out<<<128 * 16, 256, 0, stream>>>(Vw, attn, out);
}